// Round 9
// baseline (113.888 us; speedup 1.0000x reference)
//
#include <hip/hip_runtime.h>
#include <hip/hip_bf16.h>

// Co-attention layer, factorized + packed VOP3P + 2 elements/thread.
//   G_pre[l,r] = x_l*x_r*C1[l,r] + x_l*C2[l,r] + x_r*C3[l,r] + C4[l,r]
//   (C1..C4 weight-only, precomputed into d_ws, pre-scaled by 2*log2e)
//   tanh(g) = 1 - 2*rcp(exp2(g')+1); softmax shift-invariance -> only
//   S = sum rcp(...) accumulated, softmax arg = -2*log2e*S.
// Each thread handles elements (t, t+B/2): the per-l scalar-cache loads of
// the C-table (the suspected stall source) are shared by TWO independent
// tanh chains -> stalls/element halve, ILP doubles. Both element streams
// stay lane-coalesced.
// (Resubmission of R8 — previous round died on container infra, no data.)

typedef __attribute__((ext_vector_type(2))) float v2f;

#if __has_builtin(__builtin_amdgcn_exp2f)
#define EXP2F(v) __builtin_amdgcn_exp2f(v)
#else
#define EXP2F(v) exp2f(v)
#endif

#if __has_builtin(__builtin_amdgcn_rcpf)
#define RCPF(v) __builtin_amdgcn_rcpf(v)
#else
#define RCPF(v) (1.0f / (v))
#endif

#define LOG2E 1.4426950408889634f

// ---- VOP3P helpers, natural packed semantics only (R7-verified) ----
__device__ __forceinline__ v2f pk_mul_vs(v2f a, v2f s) {   // a * sgpr_pair
    v2f d; asm("v_pk_mul_f32 %0, %1, %2" : "=v"(d) : "v"(a), "s"(s)); return d;
}
__device__ __forceinline__ v2f pk_add_vs(v2f a, v2f s) {   // a + sgpr_pair
    v2f d; asm("v_pk_add_f32 %0, %1, %2" : "=v"(d) : "v"(a), "s"(s)); return d;
}
__device__ __forceinline__ v2f pk_fma_vvv(v2f a, v2f b, v2f c) {
    v2f d; asm("v_pk_fma_f32 %0, %1, %2, %3" : "=v"(d) : "v"(a), "v"(b), "v"(c)); return d;
}
__device__ __forceinline__ v2f pk_fma_vsv(v2f a, v2f s, v2f c) {  // a*sgpr + c
    v2f d; asm("v_pk_fma_f32 %0, %1, %2, %3" : "=v"(d) : "v"(a), "s"(s), "v"(c)); return d;
}
__device__ __forceinline__ v2f pk_add_vv(v2f a, v2f b) {
    v2f d; asm("v_pk_add_f32 %0, %1, %2" : "=v"(d) : "v"(a), "v"(b)); return d;
}
__device__ __forceinline__ v2f pk_mul_vv(v2f a, v2f b) {
    v2f d; asm("v_pk_mul_f32 %0, %1, %2" : "=v"(d) : "v"(a), "v"(b)); return d;
}

// ---------------- setup: C1..C4 (4 x 16 x 16 floats) into d_ws ----------------
__global__ __launch_bounds__(256) void coattn_setup(
    const float* __restrict__ emb_W,
    const float* __restrict__ emb_b,
    const float* __restrict__ M,
    float* __restrict__ C)
{
    const int t = threadIdx.x;          // one thread per (l, r) pair
    const int l = t >> 4;
    const int r = t & 15;

    float MW[8], Mb[8];
    #pragma unroll
    for (int e = 0; e < 8; ++e) {
        float s1 = 0.0f, s2 = 0.0f;
        #pragma unroll
        for (int f = 0; f < 8; ++f) {
            float m = M[e * 8 + f];
            s1 = fmaf(m, emb_W[(16 + r) * 8 + f], s1);
            s2 = fmaf(m, emb_b[(16 + r) * 8 + f], s2);
        }
        MW[e] = s1; Mb[e] = s2;
    }
    float c1 = 0.0f, c2 = 0.0f, c3 = 0.0f, c4 = 0.0f;
    #pragma unroll
    for (int e = 0; e < 8; ++e) {
        float w = emb_W[l * 8 + e];
        float b = emb_b[l * 8 + e];
        c1 = fmaf(w, MW[e], c1);
        c2 = fmaf(w, Mb[e], c2);
        c3 = fmaf(b, MW[e], c3);
        c4 = fmaf(b, Mb[e], c4);
    }
    const float s = 2.0f * LOG2E;
    C[0 * 256 + l * 16 + r] = c1 * s;
    C[1 * 256 + l * 16 + r] = c2 * s;
    C[2 * 256 + l * 16 + r] = c3 * s;
    C[3 * 256 + l * 16 + r] = c4 * s;
}

// per-element tail: softmaxes + dense + store (inlined twice, sequential
// to cap peak VGPR pressure)
__device__ __forceinline__ void coattn_tail(
    const v2f (&xv2)[16], const v2f (&Scol)[8], const float (&Srow)[16],
    const v2f* __restrict__ dW2, const v2f* __restrict__ db2v,
    float* __restrict__ outp)
{
    const float NSCL = -2.0f * LOG2E;
    v2f av[16];                       // av[0..7]=lr pairs, av[8..15]=rl pairs
    {
        float s = 0.0f;
        #pragma unroll
        for (int k = 0; k < 8; ++k) {
            float e0 = EXP2F(Scol[k].x * NSCL);
            float e1 = EXP2F(Scol[k].y * NSCL);
            av[k] = (v2f){e0, e1};
            s += e0 + e1;
        }
        float inv = RCPF(s);
        #pragma unroll
        for (int k = 0; k < 8; ++k) { av[k].x *= inv; av[k].y *= inv; }
    }
    {
        float s = 0.0f;
        float er[16];
        #pragma unroll
        for (int l = 0; l < 16; ++l) { er[l] = EXP2F(Srow[l] * NSCL); s += er[l]; }
        float inv = RCPF(s);
        #pragma unroll
        for (int m = 0; m < 8; ++m)
            av[8 + m] = (v2f){er[2*m] * inv, er[2*m+1] * inv};
    }

    v2f o2[8];
    #pragma unroll
    for (int m = 0; m < 8; ++m) o2[m] = db2v[m];

    #pragma unroll
    for (int jp = 0; jp < 16; ++jp) {         // input rows 2jp, 2jp+1
        const v2f xa = pk_mul_vv(xv2[jp], av[jp]);
        const v2f lo = (v2f){xa.x, xa.x};
        const v2f hi = (v2f){xa.y, xa.y};
        const v2f* w0 = dW2 + (2 * jp + 0) * 8;
        const v2f* w1 = dW2 + (2 * jp + 1) * 8;
        #pragma unroll
        for (int m = 0; m < 8; ++m) {
            o2[m] = pk_fma_vsv(lo, w0[m], o2[m]);
            o2[m] = pk_fma_vsv(hi, w1[m], o2[m]);
        }
    }

    float4* op = reinterpret_cast<float4*>(outp);
    #pragma unroll
    for (int t = 0; t < 4; ++t) {
        float4 v;
        v.x = fmaxf(o2[2*t+0].x, 0.0f);
        v.y = fmaxf(o2[2*t+0].y, 0.0f);
        v.z = fmaxf(o2[2*t+1].x, 0.0f);
        v.w = fmaxf(o2[2*t+1].y, 0.0f);
        op[t] = v;
    }
}

// ---------------- main: TWO elements per thread ----------------
__global__ __launch_bounds__(256) void coattn_kernel(
    const float* __restrict__ x,
    const float* __restrict__ C,
    const float* __restrict__ dW,
    const float* __restrict__ db,
    float* __restrict__ out,
    int halfB)
{
    #pragma clang fp contract(off)

    const int t = blockIdx.x * blockDim.x + threadIdx.x;
    const size_t iA = (size_t)t;
    const size_t iB = (size_t)t + (size_t)halfB;

    // ---- load both x[32] vectors as pairs (both streams lane-coalesced) ----
    v2f xA[16], xB[16];
    {
        const float4* pa = reinterpret_cast<const float4*>(x + iA * 32);
        const float4* pb = reinterpret_cast<const float4*>(x + iB * 32);
        #pragma unroll
        for (int k = 0; k < 8; ++k) {
            float4 a = pa[k], b = pb[k];
            xA[2*k+0] = (v2f){a.x, a.y}; xA[2*k+1] = (v2f){a.z, a.w};
            xB[2*k+0] = (v2f){b.x, b.y}; xB[2*k+1] = (v2f){b.z, b.w};
        }
    }

    const v2f* Cv = reinterpret_cast<const v2f*>(C);

    v2f ScolA[8], ScolB[8];
    #pragma unroll
    for (int k = 0; k < 8; ++k) { ScolA[k] = (v2f){0,0}; ScolB[k] = (v2f){0,0}; }
    float SrowA[16], SrowB[16];
    const v2f CLAMP = (v2f){88.0f, 88.0f};

    #pragma unroll
    for (int l = 0; l < 16; ++l) {
        const float xlA = xA[l >> 1][l & 1];
        const float xlB = xB[l >> 1][l & 1];
        const v2f xlvA = (v2f){xlA, xlA};
        const v2f xlvB = (v2f){xlB, xlB};
        v2f rsA = (v2f){0,0}, rsB = (v2f){0,0};
        const v2f* C1p = Cv + 0 * 128 + l * 8;
        const v2f* C2p = Cv + 1 * 128 + l * 8;
        const v2f* C3p = Cv + 2 * 128 + l * 8;
        const v2f* C4p = Cv + 3 * 128 + l * 8;
        #pragma unroll
        for (int k = 0; k < 8; ++k) {
            const v2f c1 = C1p[k], c2 = C2p[k], c3 = C3p[k], c4 = C4p[k];
            // element A
            v2f uA = pk_mul_vs(xlvA, c1); uA = pk_add_vs(uA, c3);
            v2f qA = pk_mul_vs(xlvA, c2); qA = pk_add_vs(qA, c4);
            v2f gA = pk_fma_vvv(xA[8 + k], uA, qA);
            // element B (independent chain, same SGPR constants)
            v2f uB = pk_mul_vs(xlvB, c1); uB = pk_add_vs(uB, c3);
            v2f qB = pk_mul_vs(xlvB, c2); qB = pk_add_vs(qB, c4);
            v2f gB = pk_fma_vvv(xB[8 + k], uB, qB);

            gA = __builtin_elementwise_min(gA, CLAMP);
            gB = __builtin_elementwise_min(gB, CLAMP);
            v2f DA, DB;
            DA.x = EXP2F(gA.x) + 1.0f; DA.y = EXP2F(gA.y) + 1.0f;
            DB.x = EXP2F(gB.x) + 1.0f; DB.y = EXP2F(gB.y) + 1.0f;
            float tA = RCPF(DA.x * DA.y);
            float tB = RCPF(DB.x * DB.y);
            v2f rcA; rcA.x = DA.y * tA; rcA.y = DA.x * tA;
            v2f rcB; rcB.x = DB.y * tB; rcB.y = DB.x * tB;
            ScolA[k] = pk_add_vv(ScolA[k], rcA);
            ScolB[k] = pk_add_vv(ScolB[k], rcB);
            rsA = pk_add_vv(rsA, rcA);
            rsB = pk_add_vv(rsB, rcB);
        }
        SrowA[l] = rsA.x + rsA.y;
        SrowB[l] = rsB.x + rsB.y;
    }

    const v2f* dW2  = reinterpret_cast<const v2f*>(dW);
    const v2f* db2v = reinterpret_cast<const v2f*>(db);
    coattn_tail(xA, ScolA, SrowA, dW2, db2v, out + iA * 16);
    coattn_tail(xB, ScolB, SrowB, dW2, db2v, out + iB * 16);
}

extern "C" void kernel_launch(void* const* d_in, const int* in_sizes, int n_in,
                              void* d_out, int out_size, void* d_ws, size_t ws_size,
                              hipStream_t stream) {
    const float* x     = (const float*)d_in[0];
    const float* emb_W = (const float*)d_in[1];
    const float* emb_b = (const float*)d_in[2];
    const float* M     = (const float*)d_in[3];
    const float* dW    = (const float*)d_in[4];
    const float* db    = (const float*)d_in[5];
    float* out = (float*)d_out;
    float* C   = (float*)d_ws;          // 4 * 256 floats = 4 KB

    hipLaunchKernelGGL(coattn_setup, dim3(1), dim3(256), 0, stream,
                       emb_W, emb_b, M, C);

    const int B = in_sizes[0] / 32;     // 262144
    const int halfB = B / 2;            // 131072
    dim3 block(256);
    dim3 grid(halfB / 256);             // 512 blocks
    hipLaunchKernelGGL(coattn_kernel, grid, block, 0, stream,
                       x, C, dW, db, out, halfB);
}